// Round 1
// baseline (1808.476 us; speedup 1.0000x reference)
//
#include <hip/hip_runtime.h>
#include <hip/hip_bf16.h>
#include <math.h>

// Problem constants (fixed by setup_inputs)
#define NB    16384   // batch
#define XDIM  2000
#define HDIM  100
#define ZDIM  20
#define K1K   4000    // 2*XDIM
#define LN_EPSF 1e-5f

// ---------------- math helpers ----------------
__device__ __forceinline__ float softplusf(float x) {
  // stable log(1+exp(x)) = max(x,0) + log1p(exp(-|x|))
  return fmaxf(x, 0.0f) + log1pf(expf(-fabsf(x)));
}
__device__ __forceinline__ float sigmoidf_(float x) {
  return 1.0f / (1.0f + expf(-x));
}
__device__ __forceinline__ float geluf(float x) {
  return 0.5f * x * (1.0f + erff(x * 0.70710678118654752440f));
}
__device__ __forceinline__ float wave_bcast_sum(float v) {
  #pragma unroll
  for (int off = 32; off > 0; off >>= 1) v += __shfl_down(v, off, 64);
  return __shfl(v, 0, 64);
}

// ---------------- K1/K2: GEMM (K-split concat input) + LayerNorm + GELU ----
// out[r][c] = gelu(LN_row(x[r,:] @ W + bias)), N = HDIM = 100
// Block: 320 threads, tile 64 rows x 100 cols, micro 4 rows x 5 cols.
template<int BK>
__global__ __launch_bounds__(320, 1)
void k_gemm_ln_gelu(const float* __restrict__ xA, const float* __restrict__ xB,
                    int Ksplit, int K, int ldx,
                    const float* __restrict__ W, const float* __restrict__ bias,
                    float* __restrict__ out) {
  __shared__ __align__(16) float xT[BK][68];     // transposed x tile [k][row]
  __shared__ float wS[BK][104];                  // weight tile [k][col]
  __shared__ float outS[64][105];                // epilogue tile (padded, 105%32 odd-ish)
  __shared__ float mArr[64], rArr[64];

  const int tid = threadIdx.x;
  const int tx = tid % 20;        // col group
  const int ty = tid / 20;        // row group (0..15)
  const int row0 = blockIdx.x * 64;

  float acc[4][5];
  #pragma unroll
  for (int i = 0; i < 4; ++i)
    #pragma unroll
    for (int j = 0; j < 5; ++j) acc[i][j] = 0.0f;

  for (int k0 = 0; k0 < K; k0 += BK) {
    // stage x tile: 64*BK elements, transposed into LDS
    #pragma unroll
    for (int i = 0; i < (64 * BK) / 320; ++i) {
      int idx = tid + 320 * i;
      int r = idx / BK, kk = idx % BK;
      int k = k0 + kk;
      float v;
      if (k < Ksplit) v = xA[(size_t)(row0 + r) * ldx + k];
      else            v = xB[(size_t)(row0 + r) * ldx + (k - Ksplit)];
      xT[kk][r] = v;
    }
    // stage W tile: BK*100 elements
    #pragma unroll
    for (int i = 0; i < (BK * HDIM + 319) / 320; ++i) {
      int idx = tid + 320 * i;
      if (idx < BK * HDIM) {
        int kk = idx / HDIM, c = idx % HDIM;
        wS[kk][c] = W[(size_t)(k0 + kk) * HDIM + c];
      }
    }
    __syncthreads();
    #pragma unroll 4
    for (int kk = 0; kk < BK; ++kk) {
      float4 xv = *(const float4*)&xT[kk][ty * 4];
      float xa[4] = {xv.x, xv.y, xv.z, xv.w};
      float wv[5];
      #pragma unroll
      for (int j = 0; j < 5; ++j) wv[j] = wS[kk][tx + 20 * j];
      #pragma unroll
      for (int i = 0; i < 4; ++i)
        #pragma unroll
        for (int j = 0; j < 5; ++j) acc[i][j] = fmaf(xa[i], wv[j], acc[i][j]);
    }
    __syncthreads();
  }

  // epilogue: +bias, LayerNorm over 100, GELU
  #pragma unroll
  for (int i = 0; i < 4; ++i)
    #pragma unroll
    for (int j = 0; j < 5; ++j)
      outS[ty * 4 + i][tx + 20 * j] = acc[i][j] + bias[tx + 20 * j];
  __syncthreads();
  if (tid < 64) {
    float s = 0.0f;
    for (int c = 0; c < HDIM; ++c) s += outS[tid][c];
    float m = s * (1.0f / HDIM);
    float v = 0.0f;
    for (int c = 0; c < HDIM; ++c) { float d = outS[tid][c] - m; v = fmaf(d, d, v); }
    mArr[tid] = m;
    rArr[tid] = rsqrtf(v * (1.0f / HDIM) + LN_EPSF);
  }
  __syncthreads();
  #pragma unroll
  for (int i = 0; i < 20; ++i) {
    int idx = tid + 320 * i;          // 6400 = 64*100
    int r = idx / HDIM, c = idx % HDIM;
    float y = (outS[r][c] - mArr[r]) * rArr[r];
    out[(size_t)(row0 + r) * HDIM + c] = geluf(y);
  }
}

// ---------------- K3: latent heads, reparam, enc_d, decoder front JVP ------
// One wave (64 lanes) per row; 4 rows per 256-thread block.
__global__ __launch_bounds__(256, 1)
void k_latent(const float* __restrict__ h2g,
              const float* __restrict__ eps_z, const float* __restrict__ eps_d,
              const float* __restrict__ ez_wmu, const float* __restrict__ ez_bmu,
              const float* __restrict__ ez_wlv, const float* __restrict__ ez_blv,
              const float* __restrict__ ed_w1, const float* __restrict__ ed_b1,
              const float* __restrict__ ed_wmu, const float* __restrict__ ed_bmu,
              const float* __restrict__ ed_wlv, const float* __restrict__ ed_blv,
              const float* __restrict__ dz_w1, const float* __restrict__ dz_b1,
              float* __restrict__ o_z, float* __restrict__ o_dz,
              float* __restrict__ o_muz, float* __restrict__ o_scz,
              float* __restrict__ o_mud, float* __restrict__ o_scd,
              float* __restrict__ hdec, float* __restrict__ dhdec) {
  __shared__ float sh[4][HDIM];                 // h2 row, later reused as hd row
  __shared__ float shz[4][ZDIM], shdz[4][ZDIM], shsc[4][ZDIM];
  const int tid = threadIdx.x;
  const int w = tid >> 6, lane = tid & 63;
  const int row = blockIdx.x * 4 + w;
  const size_t r20 = (size_t)row * ZDIM;
  const size_t r100 = (size_t)row * HDIM;

  const int i1 = lane;
  const bool has2 = lane < (HDIM - 64);         // lanes 0..35 own index lane+64
  const int i2 = has2 ? lane + 64 : 0;

  for (int e = lane; e < HDIM; e += 64) sh[w][e] = h2g[r100 + e];
  __syncthreads();

  // ---- heads z: mu_z (lanes 0..19), logvar->softplus (lanes 20..39)
  float accz = 0.0f;
  {
    const int j = lane % ZDIM;
    const float* Wp = (lane < ZDIM) ? ez_wmu : ez_wlv;
    if (lane < 2 * ZDIM) {
      for (int k = 0; k < HDIM; ++k) accz = fmaf(sh[w][k], Wp[k * ZDIM + j], accz);
      accz += (lane < ZDIM) ? ez_bmu[j] : ez_blv[j];
    }
    if (lane >= ZDIM && lane < 2 * ZDIM) {
      float sc = softplusf(accz);
      o_scz[r20 + j] = sc;
      shsc[w][j] = sc;
    }
    if (lane < ZDIM) o_muz[r20 + j] = accz;
  }
  __syncthreads();
  if (lane < ZDIM) {
    float zv = fmaf(shsc[w][lane], eps_z[r20 + lane], accz);
    o_z[r20 + lane] = zv;
    shz[w][lane] = zv;
  }
  __syncthreads();

  // ---- hd = gelu(LN(z @ ed_w1 + ed_b1)), overwrite sh with hd
  {
    float p1 = ed_b1[i1];
    float p2 = ed_b1[i2];
    for (int k = 0; k < ZDIM; ++k) {
      float zk = shz[w][k];
      p1 = fmaf(zk, ed_w1[k * HDIM + i1], p1);
      p2 = fmaf(zk, ed_w1[k * HDIM + i2], p2);
    }
    float m = wave_bcast_sum(p1 + (has2 ? p2 : 0.0f)) * (1.0f / HDIM);
    float d1 = p1 - m, d2 = p2 - m;
    float vv = wave_bcast_sum(d1 * d1 + (has2 ? d2 * d2 : 0.0f)) * (1.0f / HDIM);
    float rin = rsqrtf(vv + LN_EPSF);
    sh[w][i1] = geluf(d1 * rin);
    if (has2) sh[w][i2] = geluf(d2 * rin);
  }
  __syncthreads();

  // ---- heads d
  float accd = 0.0f;
  {
    const int j = lane % ZDIM;
    const float* Wp = (lane < ZDIM) ? ed_wmu : ed_wlv;
    if (lane < 2 * ZDIM) {
      for (int k = 0; k < HDIM; ++k) accd = fmaf(sh[w][k], Wp[k * ZDIM + j], accd);
      accd += (lane < ZDIM) ? ed_bmu[j] : ed_blv[j];
    }
    if (lane >= ZDIM && lane < 2 * ZDIM) {
      float sc = softplusf(accd);
      o_scd[r20 + j] = sc;
      shsc[w][j] = sc;
    }
    if (lane < ZDIM) o_mud[r20 + j] = accd;
  }
  __syncthreads();
  if (lane < ZDIM) {
    float dzv = fmaf(shsc[w][lane], eps_d[r20 + lane], accd);
    o_dz[r20 + lane] = dzv;
    shdz[w][lane] = dzv;
  }
  __syncthreads();

  // ---- decoder front: a = z@dz_w1+b1, da = dz@dz_w1; LN-JVP; GELU-JVP
  {
    float a1 = dz_b1[i1], a2 = dz_b1[i2];
    float da1 = 0.0f, da2 = 0.0f;
    for (int k = 0; k < ZDIM; ++k) {
      float zk = shz[w][k], dk = shdz[w][k];
      float w1v = dz_w1[k * HDIM + i1];
      float w2v = dz_w1[k * HDIM + i2];
      a1 = fmaf(zk, w1v, a1);  da1 = fmaf(dk, w1v, da1);
      a2 = fmaf(zk, w2v, a2);  da2 = fmaf(dk, w2v, da2);
    }
    float m  = wave_bcast_sum(a1  + (has2 ? a2  : 0.0f)) * (1.0f / HDIM);
    float dm = wave_bcast_sum(da1 + (has2 ? da2 : 0.0f)) * (1.0f / HDIM);
    float c1 = a1 - m,   c2 = a2 - m;
    float e1 = da1 - dm, e2 = da2 - dm;
    float vv  = wave_bcast_sum(c1 * c1 + (has2 ? c2 * c2 : 0.0f)) * (1.0f / HDIM);
    float cdc = wave_bcast_sum(c1 * e1 + (has2 ? c2 * e2 : 0.0f)) * (1.0f / HDIM);
    float rin = rsqrtf(vv + LN_EPSF);
    float r3c = rin * rin * rin * cdc;
    float y1 = c1 * rin, y2 = c2 * rin;
    float dy1 = e1 * rin - c1 * r3c;
    float dy2 = e2 * rin - c2 * r3c;
    float P1 = 0.5f * (1.0f + erff(y1 * 0.70710678118654752440f));
    float q1 = 0.39894228040143267794f * expf(-0.5f * y1 * y1);
    hdec[r100 + i1]  = y1 * P1;
    dhdec[r100 + i1] = (P1 + y1 * q1) * dy1;
    if (has2) {
      float P2 = 0.5f * (1.0f + erff(y2 * 0.70710678118654752440f));
      float q2 = 0.39894228040143267794f * expf(-0.5f * y2 * y2);
      hdec[r100 + i2]  = y2 * P2;
      dhdec[r100 + i2] = (P2 + y2 * q2) * dy2;
    }
  }
}

// ---------------- K4: dual GEMM (l = h@W2+b2, dl = dh@W2) + softplus/sigmoid
// + per-row partial sums. Tile 64 rows x 128 cols, 256 threads, micro 4x8 x2.
__global__ __launch_bounds__(256, 1)
void k_dec_gemm(const float* __restrict__ hdec, const float* __restrict__ dhdec,
                const float* __restrict__ W2, const float* __restrict__ b2,
                float* __restrict__ ld_out, float* __restrict__ dld_out,
                float* __restrict__ sum_ld, float* __restrict__ sum_dld) {
  __shared__ __align__(16) float hT[20][68];
  __shared__ __align__(16) float dhT[20][68];
  __shared__ __align__(16) float wS[20][132];
  __shared__ float rs_l[64], rs_d[64];
  const int tid = threadIdx.x;
  const int tx = tid & 15, ty = tid >> 4;
  const int row0 = blockIdx.y * 64, n0 = blockIdx.x * 128;

  float accl[4][8], accd[4][8];
  #pragma unroll
  for (int i = 0; i < 4; ++i)
    #pragma unroll
    for (int j = 0; j < 8; ++j) { accl[i][j] = 0.0f; accd[i][j] = 0.0f; }

  for (int k0 = 0; k0 < HDIM; k0 += 20) {
    #pragma unroll
    for (int i = 0; i < 5; ++i) {            // 64*20/256
      int idx = tid + 256 * i;
      int r = idx / 20, kk = idx % 20;
      size_t g = (size_t)(row0 + r) * HDIM + (k0 + kk);
      hT[kk][r]  = hdec[g];
      dhT[kk][r] = dhdec[g];
    }
    #pragma unroll
    for (int i = 0; i < 10; ++i) {           // 20*128/256
      int idx = tid + 256 * i;
      int kk = idx >> 7, c = idx & 127;
      int n = n0 + c;
      wS[kk][c] = (n < XDIM) ? W2[(size_t)(k0 + kk) * XDIM + n] : 0.0f;
    }
    __syncthreads();
    #pragma unroll 4
    for (int kk = 0; kk < 20; ++kk) {
      float4 hv = *(const float4*)&hT[kk][ty * 4];
      float4 dv = *(const float4*)&dhT[kk][ty * 4];
      float4 w0 = *(const float4*)&wS[kk][tx * 8];
      float4 w1 = *(const float4*)&wS[kk][tx * 8 + 4];
      float ha[4]  = {hv.x, hv.y, hv.z, hv.w};
      float dha[4] = {dv.x, dv.y, dv.z, dv.w};
      float wv[8]  = {w0.x, w0.y, w0.z, w0.w, w1.x, w1.y, w1.z, w1.w};
      #pragma unroll
      for (int i = 0; i < 4; ++i)
        #pragma unroll
        for (int j = 0; j < 8; ++j) {
          accl[i][j] = fmaf(ha[i],  wv[j], accl[i][j]);
          accd[i][j] = fmaf(dha[i], wv[j], accd[i][j]);
        }
    }
    __syncthreads();
  }

  if (tid < 64) { rs_l[tid] = 0.0f; rs_d[tid] = 0.0f; }
  __syncthreads();

  const int nb = n0 + tx * 8;
  float bv[8];
  if (nb < XDIM) {
    float4 b0 = *(const float4*)&b2[nb];
    float4 b1 = *(const float4*)&b2[nb + 4];
    bv[0] = b0.x; bv[1] = b0.y; bv[2] = b0.z; bv[3] = b0.w;
    bv[4] = b1.x; bv[5] = b1.y; bv[6] = b1.z; bv[7] = b1.w;
  }
  #pragma unroll
  for (int i = 0; i < 4; ++i) {
    int r = ty * 4 + i;
    float sl = 0.0f, sd = 0.0f;
    if (nb < XDIM) {
      float lv[8], dv2[8];
      #pragma unroll
      for (int j = 0; j < 8; ++j) {
        float l = accl[i][j] + bv[j];
        float ldv = softplusf(l);
        float dldv = sigmoidf_(l) * accd[i][j];
        lv[j] = ldv; dv2[j] = dldv;
        sl += ldv; sd += dldv;
      }
      size_t g = (size_t)(row0 + r) * XDIM + nb;
      *(float4*)&ld_out[g]      = make_float4(lv[0], lv[1], lv[2], lv[3]);
      *(float4*)&ld_out[g + 4]  = make_float4(lv[4], lv[5], lv[6], lv[7]);
      *(float4*)&dld_out[g]     = make_float4(dv2[0], dv2[1], dv2[2], dv2[3]);
      *(float4*)&dld_out[g + 4] = make_float4(dv2[4], dv2[5], dv2[6], dv2[7]);
    }
    atomicAdd(&rs_l[r], sl);
    atomicAdd(&rs_d[r], sd);
  }
  __syncthreads();
  if (tid < 64) {
    atomicAdd(&sum_ld[row0 + tid],  rs_l[tid]);
    atomicAdd(&sum_dld[row0 + tid], rs_d[tid]);
  }
}

// ---------------- K5: finalize (in-place on s_hat/diff slots) --------------
__global__ __launch_bounds__(256, 1)
void k_final(float* __restrict__ shat, float* __restrict__ diff, float* __restrict__ pu,
             const float* __restrict__ sum_ld, const float* __restrict__ sum_dld,
             const float* __restrict__ logbeta, const float* __restrict__ loggamma) {
  const int row = blockIdx.y;
  const int n = blockIdx.x * 256 + threadIdx.x;
  if (n >= XDIM) return;
  size_t off = (size_t)row * XDIM + n;
  float ldv = shat[off], dldv = diff[off];
  float m  = sum_ld[row]  * (1.0f / XDIM);
  float md = sum_dld[row] * (1.0f / XDIM);
  float invm = 1.0f / m;
  float sh = ldv * invm;
  float jv = dldv * invm - ldv * md * invm * invm;
  float df = 0.01f * jv;                 // D_COEFF
  float g  = softplusf(loggamma[n]);     // * DT (=1)
  float bt = softplusf(logbeta[n]);
  float raw = (df + sh * g) / bt;
  shat[off] = sh;
  diff[off] = df;
  pu[off]   = fmaxf(raw, 0.0f);
}

// ---------------- launch ----------------
extern "C" void kernel_launch(void* const* d_in, const int* in_sizes, int n_in,
                              void* d_out, int out_size, void* d_ws, size_t ws_size,
                              hipStream_t stream) {
  (void)in_sizes; (void)n_in; (void)out_size; (void)ws_size;
  const float* s       = (const float*)d_in[0];
  const float* u       = (const float*)d_in[1];
  const float* eps_z   = (const float*)d_in[2];
  const float* eps_d   = (const float*)d_in[3];
  const float* ez_w1   = (const float*)d_in[4];
  const float* ez_b1   = (const float*)d_in[5];
  const float* ez_w2   = (const float*)d_in[6];
  const float* ez_b2   = (const float*)d_in[7];
  const float* ez_wmu  = (const float*)d_in[8];
  const float* ez_bmu  = (const float*)d_in[9];
  const float* ez_wlv  = (const float*)d_in[10];
  const float* ez_blv  = (const float*)d_in[11];
  const float* ed_w1   = (const float*)d_in[12];
  const float* ed_b1   = (const float*)d_in[13];
  const float* ed_wmu  = (const float*)d_in[14];
  const float* ed_bmu  = (const float*)d_in[15];
  const float* ed_wlv  = (const float*)d_in[16];
  const float* ed_blv  = (const float*)d_in[17];
  const float* dz_w1   = (const float*)d_in[18];
  const float* dz_b1   = (const float*)d_in[19];
  const float* dz_w2   = (const float*)d_in[20];
  const float* dz_b2   = (const float*)d_in[21];
  const float* logbeta = (const float*)d_in[22];
  const float* loggamma= (const float*)d_in[23];

  float* out = (float*)d_out;
  float* o_z   = out;
  float* o_dz  = out + (size_t)1 * NB * ZDIM;
  float* o_muz = out + (size_t)2 * NB * ZDIM;
  float* o_scz = out + (size_t)3 * NB * ZDIM;
  float* o_mud = out + (size_t)4 * NB * ZDIM;
  float* o_scd = out + (size_t)5 * NB * ZDIM;
  float* o_shat = out + (size_t)6 * NB * ZDIM;
  float* o_diff = o_shat + (size_t)NB * XDIM;
  float* o_pu   = o_diff + (size_t)NB * XDIM;

  float* ws = (float*)d_ws;
  float* h1    = ws;
  float* h2    = ws + (size_t)1 * NB * HDIM;
  float* hdec  = ws + (size_t)2 * NB * HDIM;
  float* dhdec = ws + (size_t)3 * NB * HDIM;
  float* suml  = ws + (size_t)4 * NB * HDIM;
  float* sumd  = suml + NB;

  hipMemsetAsync(suml, 0, 2 * (size_t)NB * sizeof(float), stream);

  // K1: h1 = lingelu(concat(s,u) @ ez_w1 + ez_b1)
  k_gemm_ln_gelu<20><<<NB / 64, 320, 0, stream>>>(s, u, XDIM, K1K, XDIM, ez_w1, ez_b1, h1);
  // K2: h2 = lingelu(h1 @ ez_w2 + ez_b2)
  k_gemm_ln_gelu<20><<<NB / 64, 320, 0, stream>>>(h1, h1, HDIM, HDIM, HDIM, ez_w2, ez_b2, h2);
  // K3: heads, reparam, enc_d, decoder-front JVP
  k_latent<<<NB / 4, 256, 0, stream>>>(h2, eps_z, eps_d,
      ez_wmu, ez_bmu, ez_wlv, ez_blv,
      ed_w1, ed_b1, ed_wmu, ed_bmu, ed_wlv, ed_blv,
      dz_w1, dz_b1,
      o_z, o_dz, o_muz, o_scz, o_mud, o_scd, hdec, dhdec);
  // K4: decoder dual GEMM -> ld (in s_hat slot), dld (in diff slot) + row sums
  k_dec_gemm<<<dim3(16, NB / 64), 256, 0, stream>>>(hdec, dhdec, dz_w2, dz_b2,
      o_shat, o_diff, suml, sumd);
  // K5: finalize s_hat / diff / pu in place
  k_final<<<dim3(8, NB), 256, 0, stream>>>(o_shat, o_diff, o_pu, suml, sumd,
      logbeta, loggamma);
}